// Round 3
// baseline (203.769 us; speedup 1.0000x reference)
//
#include <hip/hip_runtime.h>
#include <hip/hip_bf16.h>
#include <math.h>

typedef __attribute__((ext_vector_type(8))) short short8;
typedef __attribute__((ext_vector_type(4))) float f32x4;

#define NROWS 64

// ---------------------------------------------------------------------------
// Kernel 1: per-row cross-entropy + logits pass-through copy.
// ---------------------------------------------------------------------------
__global__ __launch_bounds__(256) void ce_kernel(
    const float* __restrict__ logits, const int* __restrict__ target,
    float* __restrict__ out_copy, float* __restrict__ ce_rows)
{
    const int row = blockIdx.x;
    const float* x = logits + row * 1000;
    const int t = threadIdx.x;
    __shared__ float red[256];

    float m = -INFINITY;
    for (int i = t; i < 1000; i += 256) {
        float v = x[i];
        out_copy[row * 1000 + i] = v;
        m = fmaxf(m, v);
    }
    red[t] = m; __syncthreads();
    for (int s = 128; s > 0; s >>= 1) {
        if (t < s) red[t] = fmaxf(red[t], red[t + s]);
        __syncthreads();
    }
    m = red[0];
    __syncthreads();

    float ssum = 0.f;
    for (int i = t; i < 1000; i += 256) ssum += expf(x[i] - m);
    red[t] = ssum; __syncthreads();
    for (int s = 128; s > 0; s >>= 1) {
        if (t < s) red[t] += red[t + s];
        __syncthreads();
    }
    if (t == 0) {
        double lse = (double)m + log((double)red[0]);
        int tg = target[row];
        ce_rows[row] = (float)(-((double)x[tg] - lse));
    }
}

// round-to-nearest-even fp32 -> bf16 bits
__device__ __forceinline__ unsigned int bf16_rn(float x) {
    unsigned int u = __float_as_uint(x);
    return (u + 0x7FFFu + ((u >> 16) & 1u)) >> 16;
}

// ---------------------------------------------------------------------------
// Kernel 2: partial Gram via split-bf16 MFMA, fragments loaded DIRECTLY from
// global (no staging LDS, no barriers in the K-loop). Each wave owns a 32-k
// window of each 128-k chunk: lane (quad,m) loads rows tm*16+m at
// k0+quad*8 (8 fp32 = 2x dwordx4, all 8 loads independent and clustered),
// converts to hi/lo bf16 in registers, and runs 48 MFMAs into the full
// 64x64 accumulator. Waves free-run; single LDS reduce at the end.
// ---------------------------------------------------------------------------
__global__ __launch_bounds__(256) void gram_kernel(
    const float* __restrict__ A, const float* __restrict__ B,
    float* __restrict__ partials, int nA, int nB)
{
    __shared__ float kbuf[4096];

    const int blk = blockIdx.x;
    const float* X;
    int subs, strideBlocks, c;
    if (blk < 3 * nA) {
        int f = blk / nA; c = blk % nA;
        X = A + (size_t)f * NROWS * 65536;
        subs = 65536 / 128;
        strideBlocks = nA;
    } else {
        int b2 = blk - 3 * nA;
        int f = b2 / nB; c = b2 % nB;
        X = B + (size_t)f * NROWS * 32768;
        subs = 32768 / 128;
        strideBlocks = nB;
    }
    const int D = subs * 128;

    const int t = threadIdx.x;
    const int wave = t >> 6, lane = t & 63;
    const int m = lane & 15, quad = lane >> 4;

    f32x4 acc[4][4];
#pragma unroll
    for (int i = 0; i < 4; ++i)
#pragma unroll
        for (int j = 0; j < 4; ++j) acc[i][j] = (f32x4)0.f;

    for (int s = c; s < subs; s += strideBlocks) {
        const int k0 = s * 128 + (wave << 5) + (quad << 3);
        // ---- 8 independent dwordx4 loads, clustered before any use ----
        float4 fa[4], fb[4];
#pragma unroll
        for (int tm = 0; tm < 4; ++tm) {
            const float* p = X + (size_t)(tm * 16 + m) * D + k0;
            fa[tm] = *(const float4*)p;
            fb[tm] = *(const float4*)(p + 4);
        }
        // ---- convert to hi/lo bf16 fragments ----
        short8 hf[4], lf[4];
#pragma unroll
        for (int tm = 0; tm < 4; ++tm) {
            float vv[8] = {fa[tm].x, fa[tm].y, fa[tm].z, fa[tm].w,
                           fb[tm].x, fb[tm].y, fb[tm].z, fb[tm].w};
#pragma unroll
            for (int j = 0; j < 8; ++j) {
                unsigned int hb = bf16_rn(vv[j]);
                hf[tm][j] = (short)hb;
                float hfv = __uint_as_float(hb << 16);
                lf[tm][j] = (short)bf16_rn(vv[j] - hfv);
            }
        }
        // ---- 48 MFMAs: hi.hi + hi.lo + lo.hi ----
#pragma unroll
        for (int tm = 0; tm < 4; ++tm)
#pragma unroll
            for (int tn = 0; tn < 4; ++tn) {
                acc[tm][tn] = __builtin_amdgcn_mfma_f32_16x16x32_bf16(
                    hf[tm], hf[tn], acc[tm][tn], 0, 0, 0);
                acc[tm][tn] = __builtin_amdgcn_mfma_f32_16x16x32_bf16(
                    hf[tm], lf[tn], acc[tm][tn], 0, 0, 0);
                acc[tm][tn] = __builtin_amdgcn_mfma_f32_16x16x32_bf16(
                    lf[tm], hf[tn], acc[tm][tn], 0, 0, 0);
            }
    }

    // ---- cross-wave reduce in LDS (C layout verified in R2: absmax 0) ----
    __syncthreads();
    if (wave == 0) {
#pragma unroll
        for (int tm = 0; tm < 4; ++tm)
#pragma unroll
            for (int tn = 0; tn < 4; ++tn)
#pragma unroll
                for (int r = 0; r < 4; ++r)
                    kbuf[(tm * 16 + quad * 4 + r) * 64 + tn * 16 + m] = acc[tm][tn][r];
    }
    __syncthreads();
    if (wave != 0) {
#pragma unroll
        for (int tm = 0; tm < 4; ++tm)
#pragma unroll
            for (int tn = 0; tn < 4; ++tn)
#pragma unroll
                for (int r = 0; r < 4; ++r)
                    atomicAdd(&kbuf[(tm * 16 + quad * 4 + r) * 64 + tn * 16 + m],
                              acc[tm][tn][r]);
    }
    __syncthreads();

    float4* outp = (float4*)(partials + (size_t)blk * 4096);
    const float4* kb4 = (const float4*)kbuf;
    for (int e = t; e < 1024; e += 256) outp[e] = kb4[e];
}

// ---------------------------------------------------------------------------
// Kernel 3: sum block partials -> 7 compact K matrices, zero the diagonal.
// Grid = 7*64 blocks; block = (feature, 64-element e-chunk); the 4 wave-rows
// of the block split the j (partial-block) range, LDS-combined at the end.
// ---------------------------------------------------------------------------
__global__ __launch_bounds__(256) void reduce_kernel(
    const float* __restrict__ partials, float* __restrict__ K, int nA, int nB)
{
    __shared__ double red[256];
    const int f = blockIdx.x >> 6;
    const int e = ((blockIdx.x & 63) << 6) + (threadIdx.x & 63);
    const int jg = threadIdx.x >> 6;
    int base, cnt;
    if (f < 3) { base = f * nA; cnt = nA; }
    else       { base = 3 * nA + (f - 3) * nB; cnt = nB; }

    double s0 = 0.0, s1 = 0.0, s2 = 0.0, s3 = 0.0;
    int j = jg;
    for (; j + 12 < cnt; j += 16) {
        s0 += (double)partials[(size_t)(base + j)      * 4096 + e];
        s1 += (double)partials[(size_t)(base + j + 4)  * 4096 + e];
        s2 += (double)partials[(size_t)(base + j + 8)  * 4096 + e];
        s3 += (double)partials[(size_t)(base + j + 12) * 4096 + e];
    }
    for (; j < cnt; j += 4)
        s0 += (double)partials[(size_t)(base + j) * 4096 + e];
    red[threadIdx.x] = (s0 + s1) + (s2 + s3);
    __syncthreads();
    if (jg == 0) {
        double tot = red[threadIdx.x] + red[threadIdx.x + 64] +
                     red[threadIdx.x + 128] + red[threadIdx.x + 192];
        int rr = e >> 6, cc = e & 63;
        K[f * 4096 + e] = (rr == cc) ? 0.f : (float)tot;
    }
}

// ---------------------------------------------------------------------------
// Kernel 4: one block per (i,j) pair -> unbiased HSIC(Ki,Kj) in fp64.
// ---------------------------------------------------------------------------
__global__ __launch_bounds__(256) void hsic_kernel(
    const float* __restrict__ K, double* __restrict__ hsic_out)
{
    const int p = blockIdx.x;
    int i, j;
    if (p < 9) { i = p / 3; j = p % 3; }
    else       { int q = p - 9; i = 3 + q / 4; j = 3 + q % 4; }
    const float* Ki = K + i * 4096;
    const float* Kj = K + j * 4096;
    const int t = threadIdx.x;

    __shared__ double red[256];
    __shared__ double ri[64], rj[64];

    double local = 0.0;
    for (int e = t; e < 4096; e += 256)
        local += (double)Ki[e] * (double)Kj[e];
    red[t] = local; __syncthreads();
    for (int s = 128; s > 0; s >>= 1) {
        if (t < s) red[t] += red[t + s];
        __syncthreads();
    }

    if (t < 64) {
        double s = 0.0;
        for (int mcol = 0; mcol < 64; ++mcol) s += (double)Ki[t * 64 + mcol];
        ri[t] = s;
    } else if (t < 128) {
        int n = t - 64;
        double s = 0.0;
        for (int mcol = 0; mcol < 64; ++mcol) s += (double)Kj[n * 64 + mcol];
        rj[n] = s;
    }
    __syncthreads();

    if (t == 0) {
        double tr = red[0];
        double rr = 0.0, si = 0.0, sj = 0.0;
        for (int n = 0; n < 64; ++n) {
            rr += ri[n] * rj[n];
            si += ri[n];
            sj += rj[n];
        }
        const double N = 64.0;
        const double c1 = (N - 1.0) * (N - 2.0);
        const double c2 = N - 2.0;
        const double c3 = N * (N - 3.0);
        hsic_out[p] = (tr + si * sj / c1 - 2.0 * rr / c2) / c3;
    }
}

// ---------------------------------------------------------------------------
// Kernel 5: combine -> loss.
// ---------------------------------------------------------------------------
__global__ __launch_bounds__(64) void final_kernel(
    const double* __restrict__ hsic, const float* __restrict__ ce_rows,
    float* __restrict__ out_loss)
{
    if (threadIdx.x != 0) return;
    double ce = 0.0;
    for (int n = 0; n < 64; ++n) ce += (double)ce_rows[n];
    ce /= 64.0;

    double cka_total = 0.0;
    for (int i = 0; i < 3; ++i)
        for (int j = 0; j < 3; ++j)
            cka_total += hsic[i * 3 + j] / sqrt(hsic[i * 3 + i] * hsic[j * 3 + j]);
    for (int i = 0; i < 4; ++i)
        for (int j = 0; j < 4; ++j)
            cka_total += hsic[9 + i * 4 + j] / sqrt(hsic[9 + i * 4 + i] * hsic[9 + j * 4 + j]);

    out_loss[0] = (float)(ce + 0.1 * cka_total);
}

// ---------------------------------------------------------------------------
extern "C" void kernel_launch(void* const* d_in, const int* in_sizes, int n_in,
                              void* d_out, int out_size, void* d_ws, size_t ws_size,
                              hipStream_t stream)
{
    const float* output  = (const float*)d_in[0];
    const int*   target  = (const int*)d_in[1];
    const float* feats_a = (const float*)d_in[2];
    const float* feats_b = (const float*)d_in[3];
    float* out = (float*)d_out;

    char* ws = (char*)d_ws;
    float*  K        = (float*)ws;                 // 114688 B
    float*  ce_rows  = (float*)(ws + 114688);      // 256 B
    double* hsic     = (double*)(ws + 114944);     // 200 B
    float*  partials = (float*)(ws + 131072);

    // 1280 blocks (2 chunks each) for wave-level latency hiding; halve to
    // fit the workspace if needed.
    int nA = 256, nB = 128;
    for (;;) {
        size_t need = 131072 + (size_t)(3 * nA + 4 * nB) * 4096u * 4u;
        if (need <= ws_size || (nA == 1 && nB == 1)) break;
        nA = (nA > 1) ? (nA >> 1) : 1;
        nB = (nB > 1) ? (nB >> 1) : 1;
    }
    const int nblocks = 3 * nA + 4 * nB;

    hipLaunchKernelGGL(ce_kernel, dim3(64), dim3(256), 0, stream,
                       output, target, out + 1, ce_rows);
    hipLaunchKernelGGL(gram_kernel, dim3(nblocks), dim3(256), 0, stream,
                       feats_a, feats_b, partials, nA, nB);
    hipLaunchKernelGGL(reduce_kernel, dim3(7 * 64), dim3(256), 0, stream,
                       partials, K, nA, nB);
    hipLaunchKernelGGL(hsic_kernel, dim3(25), dim3(256), 0, stream,
                       K, hsic);
    hipLaunchKernelGGL(final_kernel, dim3(1), dim3(64), 0, stream,
                       hsic, ce_rows, out);
}